// Round 11
// baseline (212.850 us; speedup 1.0000x reference)
//
#include <hip/hip_runtime.h>
#include <math.h>

#define Ec 256
#define Sc 512
#define Bc 2
#define Hc 8
#define Dc 32
#define MAXNORM (1.0f - 1e-5f)
#define NEc (Bc * Sc * Ec)
#define NROWS (Bc * Hc * Sc)   // 8192
#define NBLK 256
#define KP 4                   // K-split for proj GEMM

__device__ __forceinline__ float fullWaveSum(float v) {
#pragma unroll
  for (int m = 32; m >= 1; m >>= 1) v += __shfl_xor(v, m, 64);
  return v;
}
__device__ __forceinline__ float halfWaveSum(float v) {
#pragma unroll
  for (int m = 16; m >= 1; m >>= 1) v += __shfl_xor(v, m, 64);
  return v;
}
__device__ __forceinline__ float atanh_fast(float z) {   // z in [0, 1)
  return 0.5f * __logf((1.0f + z) / (1.0f - z));
}
__device__ __forceinline__ float tanh_fast(float a) {    // a >= 0
  float e = __expf(-2.0f * a);
  return (1.0f - e) / (1.0f + e);
}

// Manual grid barrier: one fresh counter per use (no sense reversal).
// Release/acquire via __threadfence (agent scope -> cross-XCD L2 wb/inv),
// device-scope atomics for the counter. Counters zeroed by host memsetAsync.
__device__ __forceinline__ void gridBarrier(unsigned* ctr) {
  __syncthreads();
  if (threadIdx.x == 0) {
    __threadfence();   // release all this block's prior writes
    __hip_atomic_fetch_add(ctr, 1u, __ATOMIC_RELAXED, __HIP_MEMORY_SCOPE_AGENT);
    while (__hip_atomic_load(ctr, __ATOMIC_RELAXED, __HIP_MEMORY_SCOPE_AGENT) <
           (unsigned)NBLK) {
      __builtin_amdgcn_s_sleep(2);
    }
    __threadfence();   // acquire other blocks' writes
  }
  __syncthreads();
}

// 32x64 GEMM tile, K-chunks of 64, run by a 128-thread sub-block.
// Xs stride 36 (2304 floats), Ws stride 68 (4352). Block-wide barriers:
// ALL threads of the block must call with the same nk.
__device__ __forceinline__ void gemm_tile(
    const float* __restrict__ X, const float* __restrict__ W,
    float* __restrict__ O, float* __restrict__ Xs, float* __restrict__ Ws,
    const int ltid, const int rb0, const int cb0, const int kk0, const int nk,
    const bool active) {
  const int f4 = ltid & 15;
  const int s8 = ltid >> 4;
  const int ty = ltid >> 4;
  const int tx = ltid & 15;
  float acc[4][4];
#pragma unroll
  for (int i = 0; i < 4; ++i)
#pragma unroll
    for (int j = 0; j < 4; ++j) acc[i][j] = 0.f;

  for (int c = 0; c < nk; ++c) {
    const int kk = kk0 + c * 64;
    __syncthreads();
    if (active) {
#pragma unroll
      for (int i = 0; i < 4; ++i) {
        int row = s8 + i * 8;
        float4 v = *(const float4*)&X[(size_t)(rb0 + row) * Ec + kk + f4 * 4];
        Xs[(f4 * 4 + 0) * 36 + row] = v.x;
        Xs[(f4 * 4 + 1) * 36 + row] = v.y;
        Xs[(f4 * 4 + 2) * 36 + row] = v.z;
        Xs[(f4 * 4 + 3) * 36 + row] = v.w;
      }
#pragma unroll
      for (int i = 0; i < 8; ++i) {
        int col = s8 + i * 8;
        float4 v = *(const float4*)&W[(size_t)(cb0 + col) * Ec + kk + f4 * 4];
        Ws[(f4 * 4 + 0) * 68 + col] = v.x;
        Ws[(f4 * 4 + 1) * 68 + col] = v.y;
        Ws[(f4 * 4 + 2) * 68 + col] = v.z;
        Ws[(f4 * 4 + 3) * 68 + col] = v.w;
      }
    }
    __syncthreads();
    if (active) {
#pragma unroll 8
      for (int k = 0; k < 64; ++k) {
        float4 a = *(const float4*)&Xs[k * 36 + ty * 4];
        float4 b = *(const float4*)&Ws[k * 68 + tx * 4];
        float av[4] = {a.x, a.y, a.z, a.w};
        float bv[4] = {b.x, b.y, b.z, b.w};
#pragma unroll
        for (int i = 0; i < 4; ++i)
#pragma unroll
          for (int j = 0; j < 4; ++j) acc[i][j] = fmaf(av[i], bv[j], acc[i][j]);
      }
    }
  }
  if (active) {
#pragma unroll
    for (int i = 0; i < 4; ++i) {
      float4 o = make_float4(acc[i][0], acc[i][1], acc[i][2], acc[i][3]);
      *(float4*)&O[(size_t)(rb0 + ty * 4 + i) * Ec + cb0 + tx * 4] = o;
    }
  }
}

// hyp_linear epilogue for one row of q/k/v (mx buffers are FULL results now).
__device__ __forceinline__ void qkv_stats_row(
    const float* __restrict__ x,
    const float* __restrict__ mxq, const float* __restrict__ mxk,
    const float* __restrict__ mxv,
    const float* __restrict__ bq, const float* __restrict__ bk,
    const float* __restrict__ bv,
    float* __restrict__ qo, float* __restrict__ ko, float* __restrict__ lvo,
    float* __restrict__ qno, float* __restrict__ kno,
    const int row, const int t, float (*red)[4], float* fin) {
  const int b = row >> 9;
  const int s = row & (Sc - 1);
  const size_t idx = (size_t)row * Ec + t;
  const float xv = x[idx];
  const float mq = mxq[idx];
  const float mk = mxk[idx];
  const float mv = mxv[idx];
  const float bb[3] = {bq[t], bk[t], bv[t]};
  const float mvals[3] = {mq, mk, mv};

  float vals[10] = {xv * xv,
                    mq * mq, mq * bb[0], bb[0] * bb[0],
                    mk * mk, mk * bb[1], bb[1] * bb[1],
                    mv * mv, mv * bb[2], bb[2] * bb[2]};
#pragma unroll
  for (int i = 0; i < 10; ++i) {
    float v = fullWaveSum(vals[i]);
    if ((t & 63) == 0) red[i][t >> 6] = v;
  }
  __syncthreads();
  if (t < 10) fin[t] = red[t][0] + red[t][1] + red[t][2] + red[t][3];
  __syncthreads();

  const float x2 = fin[0];
  const float xn = sqrtf(fmaxf(x2, 1e-15f));
  const float at = atanh_fast(fminf(xn, MAXNORM));  // SC = 1
  const int h = t >> 5;

#pragma unroll
  for (int m = 0; m < 3; ++m) {
    float mx2 = fin[1 + 3 * m];
    float mxb = fin[2 + 3 * m];
    float b2 = fin[3 + 3 * m];
    float mxn = sqrtf(fmaxf(mx2, 1e-15f));
    float scl = tanh_fast((mxn / xn) * at) / mxn;
    float mvv = scl * mvals[m];
    float X2 = scl * scl * mx2;
    float XY = scl * mxb;
    float numc = 1.0f + 2.0f * XY + b2;
    float den = 1.0f + 2.0f * XY + X2 * b2 + 1e-15f;
    float res = (numc * mvv + (1.0f - X2) * bb[m]) / den;
    if (m < 2) {
      res = fminf(res, MAXNORM);
      float s2 = halfWaveSum(res * res);
      if (m == 0) {
        qo[idx] = res;
        if ((t & 31) == 0) qno[(b * Hc + h) * Sc + s] = s2;
      } else {
        ko[idx] = res;
        if ((t & 31) == 0) kno[(b * Hc + h) * Sc + s] = s2;
      }
    } else {
      float vn2 = halfWaveSum(res * res);
      float vn = sqrtf(fmaxf(vn2, 1e-15f));
      float f = atanh_fast(fminf(vn, MAXNORM)) / vn;
      lvo[idx] = f * res;
    }
  }
  __syncthreads();
}

__device__ __forceinline__ void proj_stats_row(
    const float* __restrict__ xin, const float* __restrict__ mx,
    const float* __restrict__ bo, float* __restrict__ out,
    const int row, const int t, float (*red)[4], float* fin) {
  const size_t idx = (size_t)row * Ec + t;
  const float xv = xin[idx];
  float m = 0.f;
#pragma unroll
  for (int p = 0; p < KP; ++p) m += mx[idx + (size_t)p * NEc];
  const float bb = bo[t];
  float vals[4] = {xv * xv, m * m, m * bb, bb * bb};
#pragma unroll
  for (int i = 0; i < 4; ++i) {
    float v = fullWaveSum(vals[i]);
    if ((t & 63) == 0) red[i][t >> 6] = v;
  }
  __syncthreads();
  if (t < 4) fin[t] = red[t][0] + red[t][1] + red[t][2] + red[t][3];
  __syncthreads();

  float x2 = fin[0], mx2 = fin[1], mxb = fin[2], b2 = fin[3];
  float xn = sqrtf(fmaxf(x2, 1e-15f));
  float mxn = sqrtf(fmaxf(mx2, 1e-15f));
  float scl = tanh_fast((mxn / xn) * atanh_fast(fminf(xn, MAXNORM))) / mxn;
  float mvv = scl * m;
  float X2 = scl * scl * mx2;
  float XY = scl * mxb;
  float numc = 1.0f + 2.0f * XY + b2;
  float den = 1.0f + 2.0f * XY + X2 * b2 + 1e-15f;
  out[idx] = (numc * mvv + (1.0f - X2) * bb) / den;
  __syncthreads();
}

// ---------------------------------------------------------------------------
// Persistent kernel (NORMAL launch), 256 blocks x 512 threads, ~56 KB LDS
// -> 2 blocks/CU capacity = 512 >= 256 grid: all blocks guaranteed resident,
// so the manual gridBarrier cannot deadlock.
// ---------------------------------------------------------------------------
__global__ __launch_bounds__(512) void fused_all(
    const float* __restrict__ x,
    const float* __restrict__ Wq, const float* __restrict__ bq,
    const float* __restrict__ Wk, const float* __restrict__ bk,
    const float* __restrict__ Wv, const float* __restrict__ bv,
    const float* __restrict__ Wo, const float* __restrict__ bo,
    const float* __restrict__ hs,
    float* __restrict__ mxq, float* __restrict__ mxk, float* __restrict__ mxv,
    float* __restrict__ mxo, float* __restrict__ qb, float* __restrict__ kb,
    float* __restrict__ lvb, float* __restrict__ aob, float* __restrict__ qnb,
    float* __restrict__ knb, float* __restrict__ out, unsigned* bar) {
  __shared__ float smem[13952];
  __shared__ float red[2][10][4];
  __shared__ float fin[2][10];
  const int tid = threadIdx.x;
  const int blk = blockIdx.x;

  // ===== phase 1: qkv GEMM, full-K (nk=4), 384 tiles over 512 slots =======
  {
    const int sub = tid >> 7;            // 0..3; subs 2,3 barrier-only
    const int ltid = tid & 127;
    const int slot = blk * 2 + (sub & 1);
    const bool active = (sub < 2) && (slot < 384);
    const int s = active ? slot : 0;
    const int mat = s >> 7;              // 0..2
    const int rem = s & 127;
    const int cb0 = ((rem >> 5) & 3) * 64;
    const int rb0 = (rem & 31) * 32;
    const float* W = (mat == 0) ? Wq : (mat == 1) ? Wk : Wv;
    float* O = (mat == 0) ? mxq : (mat == 1) ? mxk : mxv;
    float* Xs = smem + (sub & 1) * 6656;
    float* Ws = Xs + 2304;
    gemm_tile(x, W, O, Xs, Ws, ltid, rb0, cb0, 0, 4, active);
  }
  gridBarrier(&bar[0]);

  // ===== phase 2: qkv hyp_linear stats (1024 rows) ==========================
  {
    const int half = tid >> 8;
    const int t = tid & 255;
    const int unit = blk * 2 + half;     // 0..511
#pragma unroll 1
    for (int iter = 0; iter < 2; ++iter) {
      qkv_stats_row(x, mxq, mxk, mxv, bq, bk, bv, qb, kb, lvb, qnb, knb,
                    unit + iter * 512, t, red[half], fin[half]);
    }
  }
  gridBarrier(&bar[1]);

  // ===== phase 3: fused hyperbolic attention (k-tiles of 128, 4 iters) =====
  {
    const int qt = blk & 15;
    const int bh = blk >> 4;
    const int b = bh >> 3;
    const int h = bh & 7;
    const int sq0 = qt * 32;

    float* Qs = smem;            // [32][32] swizzled   (0..1024)
    float* Ks = smem + 1024;     // [128][32] swizzled  (1024..5120)
    float* lvs = smem + 5120;    // [128][36]           (5120..9728)
    float* Ps = smem + 9728;     // [32][132]           (9728..13952)
    float* accm = smem + 1024;   // overlay [32][8][32] (1024..9216)
    float* lsb = smem + 9216;    // [32][8]             (9216..9472)

    const int ty = tid >> 6;     // phase A: 4 q-rows
    const int tx = tid & 63;     // phase A: 2 k-cols
    const int js = tid >> 6;     // phase B: j-slice (16 k)
    const int rg = (tid >> 3) & 7;
    const int dq = tid & 7;

    if (tid < 256) {
      int r = tid >> 3, fd = tid & 7;
      int fsw = fd ^ ((r >> 2) & 7);
      *(float4*)&Qs[r * 32 + fsw * 4] =
          *(const float4*)&qb[(size_t)(b * Sc + sq0 + r) * Ec + h * Dc + fd * 4];
    }
    const float sinv = -1.0f / (hs[h] * sqrtf((float)Dc));
    float qnv[4];
#pragma unroll
    for (int i = 0; i < 4; ++i) qnv[i] = qnb[bh * Sc + sq0 + ty * 4 + i];

    float4 oacc[4];
#pragma unroll
    for (int i = 0; i < 4; ++i) oacc[i] = make_float4(0.f, 0.f, 0.f, 0.f);
    float lsum4[4] = {0.f, 0.f, 0.f, 0.f};

#pragma unroll 1
    for (int kt = 0; kt < 4; ++kt) {
      const int k0 = kt * 128;
      __syncthreads();
#pragma unroll
      for (int i = 0; i < 2; ++i) {
        int qi = tid + i * 512;          // 0..1023
        int r = qi >> 3, fd = qi & 7;    // r 0..127
        int fsw = fd ^ ((r >> 2) & 7);
        *(float4*)&Ks[r * 32 + fsw * 4] =
            *(const float4*)&kb[(size_t)(b * Sc + k0 + r) * Ec + h * Dc + fd * 4];
        *(float4*)&lvs[r * 36 + fd * 4] =
            *(const float4*)&lvb[(size_t)(b * Sc + k0 + r) * Ec + h * Dc + fd * 4];
      }
      float knv[2];
#pragma unroll
      for (int j = 0; j < 2; ++j) knv[j] = knb[bh * Sc + k0 + tx * 2 + j];
      __syncthreads();

      // phase A: 4x2 Gram dots (Ks row tx*2+j -> swizzle key (tx>>1)&7)
      float acc[4][2];
#pragma unroll
      for (int i = 0; i < 4; ++i) {
        acc[i][0] = 0.f;
        acc[i][1] = 0.f;
      }
#pragma unroll
      for (int fd = 0; fd < 8; ++fd) {
        const int qsw = (fd ^ (ty & 7)) * 4;
        const int ksw = (fd ^ ((tx >> 1) & 7)) * 4;
        float4 a[4], bb2[2];
#pragma unroll
        for (int i = 0; i < 4; ++i)
          a[i] = *(const float4*)&Qs[(ty * 4 + i) * 32 + qsw];
#pragma unroll
        for (int j = 0; j < 2; ++j)
          bb2[j] = *(const float4*)&Ks[(tx * 2 + j) * 32 + ksw];
#pragma unroll
        for (int i = 0; i < 4; ++i)
#pragma unroll
          for (int j = 0; j < 2; ++j) {
            acc[i][j] = fmaf(a[i].x, bb2[j].x, acc[i][j]);
            acc[i][j] = fmaf(a[i].y, bb2[j].y, acc[i][j]);
            acc[i][j] = fmaf(a[i].z, bb2[j].z, acc[i][j]);
            acc[i][j] = fmaf(a[i].w, bb2[j].w, acc[i][j]);
          }
      }
      // score transform -> Ps
#pragma unroll
      for (int i = 0; i < 4; ++i) {
        const float q2 = qnv[i];
        const float omq = 1.0f - q2;
        float po[2];
#pragma unroll
        for (int j = 0; j < 2; ++j) {
          const float k2 = knv[j];
          const float kq = acc[i][j];
          const float omk = 1.0f - k2;
          float s2x2 = fmaf(-4.0f, kq, 2.0f * k2 + 2.0f * q2);   // 2||q-k||^2
          float dden = fmaf(k2, q2, fmaf(-2.0f, kq, 1.0f)) + 1e-15f;
          float Pd = fmaf(dden, omk * omq, 1e-20f);
          float rp = __builtin_amdgcn_rcpf(Pd);
          float tt = fmaxf(s2x2 * rp, 1e-7f);                    // a-1
          float z = (1.0f + tt) + sqrtf(fmaf(tt, tt, tt + tt));
          po[j] = __builtin_amdgcn_exp2f(sinv * __builtin_amdgcn_logf(z));
        }
        *(float2*)&Ps[(ty * 4 + i) * 132 + tx * 2] = make_float2(po[0], po[1]);
      }
      __syncthreads();

      // phase B: P-tile @ LV-tile (4 rows x 4 dims x 16-k slice per thread)
#pragma unroll
      for (int jq = 0; jq < 4; ++jq) {
        const int j0 = js * 16 + jq * 4;
        float4 p[4], l[4];
#pragma unroll
        for (int i = 0; i < 4; ++i)
          p[i] = *(const float4*)&Ps[(rg * 4 + i) * 132 + j0];
#pragma unroll
        for (int c = 0; c < 4; ++c)
          l[c] = *(const float4*)&lvs[(j0 + c) * 36 + dq * 4];
#pragma unroll
        for (int i = 0; i < 4; ++i) {
          lsum4[i] += (p[i].x + p[i].y) + (p[i].z + p[i].w);
          oacc[i].x = fmaf(p[i].x, l[0].x, oacc[i].x);
          oacc[i].y = fmaf(p[i].x, l[0].y, oacc[i].y);
          oacc[i].z = fmaf(p[i].x, l[0].z, oacc[i].z);
          oacc[i].w = fmaf(p[i].x, l[0].w, oacc[i].w);
          oacc[i].x = fmaf(p[i].y, l[1].x, oacc[i].x);
          oacc[i].y = fmaf(p[i].y, l[1].y, oacc[i].y);
          oacc[i].z = fmaf(p[i].y, l[1].z, oacc[i].z);
          oacc[i].w = fmaf(p[i].y, l[1].w, oacc[i].w);
          oacc[i].x = fmaf(p[i].z, l[2].x, oacc[i].x);
          oacc[i].y = fmaf(p[i].z, l[2].y, oacc[i].y);
          oacc[i].z = fmaf(p[i].z, l[2].z, oacc[i].z);
          oacc[i].w = fmaf(p[i].z, l[2].w, oacc[i].w);
          oacc[i].x = fmaf(p[i].w, l[3].x, oacc[i].x);
          oacc[i].y = fmaf(p[i].w, l[3].y, oacc[i].y);
          oacc[i].z = fmaf(p[i].w, l[3].z, oacc[i].z);
          oacc[i].w = fmaf(p[i].w, l[3].w, oacc[i].w);
        }
      }
    }

    // merge js partials + expmap0 (accm overlays Ks/lvs — barrier first)
    __syncthreads();
#pragma unroll
    for (int i = 0; i < 4; ++i)
      *(float4*)&accm[((rg * 4 + i) * 8 + js) * 32 + dq * 4] = oacc[i];
    if (dq == 0) {
#pragma unroll
      for (int i = 0; i < 4; ++i) lsb[(rg * 4 + i) * 8 + js] = lsum4[i];
    }
    __syncthreads();

    if (tid < 256) {
      const int rw = tid >> 3;
      const int d2 = tid & 7;
      float4 o = make_float4(0.f, 0.f, 0.f, 0.f);
      float ls = 0.f;
#pragma unroll
      for (int g = 0; g < 8; ++g) {
        float4 a4 = *(const float4*)&accm[(rw * 8 + g) * 32 + d2 * 4];
        o.x += a4.x; o.y += a4.y; o.z += a4.z; o.w += a4.w;
        ls += lsb[rw * 8 + g];
      }
      const float li = 1.0f / ls;
      o.x *= li; o.y *= li; o.z *= li; o.w *= li;
      float un2 = fmaf(o.x, o.x, fmaf(o.y, o.y, fmaf(o.z, o.z, o.w * o.w)));
#pragma unroll
      for (int m = 4; m >= 1; m >>= 1) un2 += __shfl_xor(un2, m, 8);
      float un = sqrtf(fmaxf(un2, 1e-15f));
      float f = tanh_fast(un) / un;
      float4 ov = make_float4(o.x * f, o.y * f, o.z * f, o.w * f);
      *(float4*)&aob[(size_t)(b * Sc + sq0 + rw) * Ec + h * Dc + d2 * 4] = ov;
    }
  }
  gridBarrier(&bar[2]);

  // ===== phase 4: proj GEMM, K-split 4 (nk=1), exactly 512 slots ===========
  {
    const int sub = tid >> 7;
    const int ltid = tid & 127;
    const int slot = blk * 2 + (sub & 1);
    const bool active = (sub < 2);
    const int kz = (slot >> 7) & 3;
    const int rem = slot & 127;
    const int cb0 = ((rem >> 5) & 3) * 64;
    const int rb0 = (rem & 31) * 32;
    float* Xs = smem + (sub & 1) * 6656;
    float* Ws = Xs + 2304;
    gemm_tile(aob, Wo, mxo + (size_t)kz * NEc, Xs, Ws, ltid, rb0, cb0,
              kz * 64, 1, active);
  }
  gridBarrier(&bar[3]);

  // ===== phase 5: proj stats (1024 rows) ===================================
  {
    const int half = tid >> 8;
    const int t = tid & 255;
    const int unit = blk * 2 + half;
#pragma unroll 1
    for (int iter = 0; iter < 2; ++iter) {
      proj_stats_row(aob, mxo, bo, out, unit + iter * 512, t,
                     red[half], fin[half]);
    }
  }
}

extern "C" void kernel_launch(void* const* d_in, const int* in_sizes, int n_in,
                              void* d_out, int out_size, void* d_ws, size_t ws_size,
                              hipStream_t stream) {
  (void)in_sizes; (void)n_in; (void)out_size; (void)ws_size;
  const float* x  = (const float*)d_in[0];
  const float* Wq = (const float*)d_in[1];
  const float* bq = (const float*)d_in[2];
  const float* Wk = (const float*)d_in[3];
  const float* bk = (const float*)d_in[4];
  const float* Wv = (const float*)d_in[5];
  const float* bv = (const float*)d_in[6];
  const float* Wo = (const float*)d_in[7];
  const float* bo = (const float*)d_in[8];
  const float* hs = (const float*)d_in[9];

  unsigned* bar = (unsigned*)d_ws;          // 4 barrier counters
  float* ws = (float*)((char*)d_ws + 256);
  float* mxq = ws;                          // NEc each (full results)
  float* mxk = mxq + NEc;
  float* mxv = mxk + NEc;
  float* mxo = mxv + NEc;                   // KP * NEc partials
  float* qb  = mxo + (size_t)KP * NEc;
  float* kb  = qb + NEc;
  float* lvb = kb + NEc;
  float* aob = lvb + NEc;
  float* qnb = aob + NEc;
  float* knb = qnb + NROWS;
  float* outp = (float*)d_out;

  hipMemsetAsync(bar, 0, 4 * sizeof(unsigned), stream);
  fused_all<<<NBLK, 512, 0, stream>>>(x, Wq, bq, Wk, bk, Wv, bv, Wo, bo, hs,
                                      mxq, mxk, mxv, mxo, qb, kb, lvb, aob,
                                      qnb, knb, outp, bar);
}

// Round 12
// 124.598 us; speedup vs baseline: 1.7083x; 1.7083x over previous
//
#include <hip/hip_runtime.h>
#include <math.h>

#define Ec 256
#define Sc 512
#define Bc 2
#define Hc 8
#define Dc 32
#define MAXNORM (1.0f - 1e-5f)
#define NEc (Bc * Sc * Ec)
#define KSQ 2                  // K-split for qkv GEMM (nk=2 chunks of 64)
#define KSO 4                  // K-split for proj GEMM (nk=1)
#define NROWS (Bc * Hc * Sc)   // 8192 (b,h,s) rows

__device__ __forceinline__ float fullWaveSum(float v) {
#pragma unroll
  for (int m = 32; m >= 1; m >>= 1) v += __shfl_xor(v, m, 64);
  return v;
}
__device__ __forceinline__ float halfWaveSum(float v) {
#pragma unroll
  for (int m = 16; m >= 1; m >>= 1) v += __shfl_xor(v, m, 64);
  return v;
}
__device__ __forceinline__ float atanh_fast(float z) {   // z in [0, 1)
  return 0.5f * __logf((1.0f + z) / (1.0f - z));
}
__device__ __forceinline__ float tanh_fast(float a) {    // a >= 0
  float e = __expf(-2.0f * a);
  return (1.0f - e) / (1.0f + e);
}

// ---------------------------------------------------------------------------
// Tiled GEMM partial: O[kz] = X[:, kz*64*nk : (kz+1)*64*nk] @ W[:, same]^T
// Tile 32 rows x 64 cols, nk K-chunks of 64. blk 128.
// ---------------------------------------------------------------------------
__global__ __launch_bounds__(128) void gemm_xwt(
    const float* __restrict__ X,
    const float* __restrict__ W0, const float* __restrict__ W1,
    const float* __restrict__ W2,
    float* __restrict__ O0, float* __restrict__ O1, float* __restrict__ O2,
    const int nk) {
  const int tid = threadIdx.x;
  const int bx = blockIdx.x;
  const int by = blockIdx.y;
  const int kz = blockIdx.z;
  const int mat = by >> 2;
  const int cb0 = (by & 3) * 64;
  const int rb0 = bx * 32;
  const int kk0 = kz * 64 * nk;
  const float* __restrict__ W = (mat == 0) ? W0 : (mat == 1) ? W1 : W2;
  float* __restrict__ O = ((mat == 0) ? O0 : (mat == 1) ? O1 : O2) + (size_t)kz * NEc;

  __shared__ float Xs[64][36];   // [k][row]
  __shared__ float Ws[64][68];   // [k][col]

  const int f4 = tid & 15;
  const int sub = tid >> 4;
  const int ty = tid >> 4;
  const int tx = tid & 15;

  float acc[4][4];
#pragma unroll
  for (int i = 0; i < 4; ++i)
#pragma unroll
    for (int j = 0; j < 4; ++j) acc[i][j] = 0.f;

  for (int c = 0; c < nk; ++c) {
    const int kk = kk0 + c * 64;
    __syncthreads();
#pragma unroll
    for (int i = 0; i < 4; ++i) {
      int row = sub + i * 8;
      float4 v = *(const float4*)&X[(size_t)(rb0 + row) * Ec + kk + f4 * 4];
      Xs[f4 * 4 + 0][row] = v.x;
      Xs[f4 * 4 + 1][row] = v.y;
      Xs[f4 * 4 + 2][row] = v.z;
      Xs[f4 * 4 + 3][row] = v.w;
    }
#pragma unroll
    for (int i = 0; i < 8; ++i) {
      int col = sub + i * 8;
      float4 v = *(const float4*)&W[(size_t)(cb0 + col) * Ec + kk + f4 * 4];
      Ws[f4 * 4 + 0][col] = v.x;
      Ws[f4 * 4 + 1][col] = v.y;
      Ws[f4 * 4 + 2][col] = v.z;
      Ws[f4 * 4 + 3][col] = v.w;
    }
    __syncthreads();
#pragma unroll 8
    for (int k = 0; k < 64; ++k) {
      float4 a = *(const float4*)&Xs[k][ty * 4];
      float4 b = *(const float4*)&Ws[k][tx * 4];
      float av[4] = {a.x, a.y, a.z, a.w};
      float bv[4] = {b.x, b.y, b.z, b.w};
#pragma unroll
      for (int i = 0; i < 4; ++i)
#pragma unroll
        for (int j = 0; j < 4; ++j) acc[i][j] = fmaf(av[i], bv[j], acc[i][j]);
    }
  }
#pragma unroll
  for (int i = 0; i < 4; ++i) {
    float4 o = make_float4(acc[i][0], acc[i][1], acc[i][2], acc[i][3]);
    *(float4*)&O[(size_t)(rb0 + ty * 4 + i) * Ec + cb0 + tx * 4] = o;
  }
}

// ---------------------------------------------------------------------------
// Per-row hyp_linear epilogue for q/k/v (sums the KSQ K-split partials)
// ---------------------------------------------------------------------------
__global__ __launch_bounds__(256) void qkv_stats(
    const float* __restrict__ x,
    const float* __restrict__ mxq, const float* __restrict__ mxk,
    const float* __restrict__ mxv,
    const float* __restrict__ bq, const float* __restrict__ bk,
    const float* __restrict__ bv,
    float* __restrict__ qo, float* __restrict__ ko, float* __restrict__ lvo,
    float* __restrict__ qno, float* __restrict__ kno) {
  const int t = threadIdx.x;
  const int row = blockIdx.x;
  const int b = row >> 9;
  const int s = row & (Sc - 1);
  const size_t idx = (size_t)row * Ec + t;
  const float xv = x[idx];
  float mq = 0.f, mk = 0.f, mv = 0.f;
#pragma unroll
  for (int p = 0; p < KSQ; ++p) {
    mq += mxq[idx + (size_t)p * NEc];
    mk += mxk[idx + (size_t)p * NEc];
    mv += mxv[idx + (size_t)p * NEc];
  }
  const float bb[3] = {bq[t], bk[t], bv[t]};
  const float mvals[3] = {mq, mk, mv};

  float vals[10] = {xv * xv,
                    mq * mq, mq * bb[0], bb[0] * bb[0],
                    mk * mk, mk * bb[1], bb[1] * bb[1],
                    mv * mv, mv * bb[2], bb[2] * bb[2]};
  __shared__ float red[10][4];
  __shared__ float fin[10];
#pragma unroll
  for (int i = 0; i < 10; ++i) {
    float v = fullWaveSum(vals[i]);
    if ((t & 63) == 0) red[i][t >> 6] = v;
  }
  __syncthreads();
  if (t < 10) fin[t] = red[t][0] + red[t][1] + red[t][2] + red[t][3];
  __syncthreads();

  const float x2 = fin[0];
  const float xn = sqrtf(fmaxf(x2, 1e-15f));
  const float at = atanh_fast(fminf(xn, MAXNORM));  // SC = 1
  const int h = t >> 5;

#pragma unroll
  for (int m = 0; m < 3; ++m) {
    float mx2 = fin[1 + 3 * m];
    float mxb = fin[2 + 3 * m];
    float b2 = fin[3 + 3 * m];
    float mxn = sqrtf(fmaxf(mx2, 1e-15f));
    float scl = tanh_fast((mxn / xn) * at) / mxn;
    float mvv = scl * mvals[m];
    float X2 = scl * scl * mx2;
    float XY = scl * mxb;
    float numc = 1.0f + 2.0f * XY + b2;
    float den = 1.0f + 2.0f * XY + X2 * b2 + 1e-15f;
    float res = (numc * mvv + (1.0f - X2) * bb[m]) / den;
    if (m < 2) {
      res = fminf(res, MAXNORM);                 // elementwise clamp_max
      float s2 = halfWaveSum(res * res);         // per-head ||.||^2 (C=1)
      if (m == 0) {
        qo[idx] = res;
        if ((t & 31) == 0) qno[(b * Hc + h) * Sc + s] = s2;
      } else {
        ko[idx] = res;
        if ((t & 31) == 0) kno[(b * Hc + h) * Sc + s] = s2;
      }
    } else {
      float vn2 = halfWaveSum(res * res);
      float vn = sqrtf(fmaxf(vn2, 1e-15f));
      float f = atanh_fast(fminf(vn, MAXNORM)) / vn;  // logmap0 factor
      lvo[idx] = f * res;
    }
  }
}

// ---------------------------------------------------------------------------
// Score kernel: P[bh][sq][sk] = z^sinv, z = a + sqrt(a^2-1), via native
// v_log_f32 (log2) + v_exp_f32 (2^x) builtins.
// 16 batched 512x512x32 GEMMs. grid (8 sk-tiles, 8 sq-tiles, 16 bh), blk 256.
// ---------------------------------------------------------------------------
__global__ __launch_bounds__(256) void score_kernel(
    const float* __restrict__ q, const float* __restrict__ k,
    const float* __restrict__ qn, const float* __restrict__ kn,
    const float* __restrict__ hs, float* __restrict__ P) {
  const int tid = threadIdx.x;
  const int sk0 = blockIdx.x * 64;
  const int sq0 = blockIdx.y * 64;
  const int bh = blockIdx.z;
  const int b = bh >> 3;
  const int h = bh & 7;

  __shared__ float Qs[64][32];
  __shared__ float Ks[64][32];

#pragma unroll
  for (int i = 0; i < 2; ++i) {
    int qi = tid + i * 256;
    int r = qi >> 3;
    int fd = qi & 7;
    int fsw = fd ^ ((r >> 2) & 7);
    float4 v = *(const float4*)&q[(size_t)(b * Sc + sq0 + r) * Ec + h * Dc + fd * 4];
    *(float4*)&Qs[r][fsw * 4] = v;
    float4 w = *(const float4*)&k[(size_t)(b * Sc + sk0 + r) * Ec + h * Dc + fd * 4];
    *(float4*)&Ks[r][fsw * 4] = w;
  }
  __syncthreads();

  const int ty = tid >> 4;
  const int tx = tid & 15;

  float acc[4][4];
#pragma unroll
  for (int i = 0; i < 4; ++i)
#pragma unroll
    for (int j = 0; j < 4; ++j) acc[i][j] = 0.f;

#pragma unroll
  for (int fd = 0; fd < 8; ++fd) {
    const int qsw = (fd ^ (ty & 7)) * 4;
    const int ksw = (fd ^ (tx & 7)) * 4;
    float4 a[4], bb[4];
#pragma unroll
    for (int i = 0; i < 4; ++i) a[i] = *(const float4*)&Qs[ty * 4 + i][qsw];
#pragma unroll
    for (int j = 0; j < 4; ++j) bb[j] = *(const float4*)&Ks[tx * 4 + j][ksw];
#pragma unroll
    for (int i = 0; i < 4; ++i)
#pragma unroll
      for (int j = 0; j < 4; ++j) {
        acc[i][j] = fmaf(a[i].x, bb[j].x, acc[i][j]);
        acc[i][j] = fmaf(a[i].y, bb[j].y, acc[i][j]);
        acc[i][j] = fmaf(a[i].z, bb[j].z, acc[i][j]);
        acc[i][j] = fmaf(a[i].w, bb[j].w, acc[i][j]);
      }
  }

  // epilogue: hyperbolic distance -> p = z^sinv via native log2/exp2
  const float sinv = -1.0f / (hs[h] * sqrtf((float)Dc));
  float qnv[4], knv[4];
#pragma unroll
  for (int i = 0; i < 4; ++i) qnv[i] = qn[bh * Sc + sq0 + ty * 4 + i];
#pragma unroll
  for (int j = 0; j < 4; ++j) knv[j] = kn[bh * Sc + sk0 + tx * 4 + j];

#pragma unroll
  for (int i = 0; i < 4; ++i) {
    const float q2 = qnv[i];
    const float omq = 1.0f - q2;
    float4 o;
    float po[4];
#pragma unroll
    for (int j = 0; j < 4; ++j) {
      const float k2 = knv[j];
      const float kq = acc[i][j];
      const float omk = 1.0f - k2;
      float s2x2 = fmaf(-4.0f, kq, 2.0f * k2 + 2.0f * q2);       // 2*||q-k||^2
      float dden = fmaf(k2, q2, fmaf(-2.0f, kq, 1.0f)) + 1e-15f;
      float Pd = fmaf(dden, omk * omq, 1e-20f);
      float rp = __builtin_amdgcn_rcpf(Pd);
      float tt = fmaxf(s2x2 * rp, 1e-7f);                        // a-1
      float z = (1.0f + tt) + sqrtf(fmaf(tt, tt, tt + tt));
      po[j] = __builtin_amdgcn_exp2f(sinv * __builtin_amdgcn_logf(z));
    }
    o.x = po[0]; o.y = po[1]; o.z = po[2]; o.w = po[3];
    *(float4*)&P[((size_t)bh * Sc + sq0 + ty * 4 + i) * Sc + sk0 + tx * 4] = o;
  }
}

// ---------------------------------------------------------------------------
// PV kernel v2: out = expmap0( (P @ LV) / rowsum(P) ).
// grid (32 sq-tiles of 16 rows, 16 bh) = 512 blocks, block 256:
//   js = tid>>5 (8 j-slices), rg = (tid>>3)&3 (4 row-quads), dq = tid&7 (4 d)
// Thread tile 4 rows x 4 dims x (8 j per 64-tile) -> 2 B/FMA LDS ratio.
// ---------------------------------------------------------------------------
__global__ __launch_bounds__(256) void pv_kernel(
    const float* __restrict__ P, const float* __restrict__ lv,
    float* __restrict__ out) {
  const int tid = threadIdx.x;
  const int sq0 = blockIdx.x * 16;
  const int bh = blockIdx.y;
  const int b = bh >> 3;
  const int h = bh & 7;
  const int js = tid >> 5;
  const int rg = (tid >> 3) & 3;
  const int dq = tid & 7;

  __shared__ float Ps[16][68];
  __shared__ float lvs[64][36];
  __shared__ float accm[16][8][32];   // [row][js][d]
  __shared__ float lsb[16][9];

  float4 acc[4];
#pragma unroll
  for (int i = 0; i < 4; ++i) acc[i] = make_float4(0.f, 0.f, 0.f, 0.f);
  float lsum4[4] = {0.f, 0.f, 0.f, 0.f};

#pragma unroll 1
  for (int t = 0; t < 8; ++t) {
    const int j0g = t * 64;
    {
      int pr = tid >> 4, pc = tid & 15;
      *(float4*)&Ps[pr][pc * 4] =
          *(const float4*)&P[((size_t)bh * Sc + sq0 + pr) * Sc + j0g + pc * 4];
#pragma unroll
      for (int i = 0; i < 2; ++i) {
        int qi = tid + i * 256;
        int lr = qi >> 3, lc = qi & 7;
        *(float4*)&lvs[lr][lc * 4] =
            *(const float4*)&lv[(size_t)(b * Sc + j0g + lr) * Ec + h * Dc + lc * 4];
      }
    }
    __syncthreads();

#pragma unroll
    for (int j4 = 0; j4 < 2; ++j4) {
      const int j0 = js * 8 + j4 * 4;
      float4 p[4], l[4];
#pragma unroll
      for (int i = 0; i < 4; ++i) p[i] = *(const float4*)&Ps[rg * 4 + i][j0];
#pragma unroll
      for (int c = 0; c < 4; ++c) l[c] = *(const float4*)&lvs[j0 + c][dq * 4];
#pragma unroll
      for (int i = 0; i < 4; ++i) {
        lsum4[i] += (p[i].x + p[i].y) + (p[i].z + p[i].w);
        acc[i].x = fmaf(p[i].x, l[0].x, acc[i].x);
        acc[i].y = fmaf(p[i].x, l[0].y, acc[i].y);
        acc[i].z = fmaf(p[i].x, l[0].z, acc[i].z);
        acc[i].w = fmaf(p[i].x, l[0].w, acc[i].w);
        acc[i].x = fmaf(p[i].y, l[1].x, acc[i].x);
        acc[i].y = fmaf(p[i].y, l[1].y, acc[i].y);
        acc[i].z = fmaf(p[i].y, l[1].z, acc[i].z);
        acc[i].w = fmaf(p[i].y, l[1].w, acc[i].w);
        acc[i].x = fmaf(p[i].z, l[2].x, acc[i].x);
        acc[i].y = fmaf(p[i].z, l[2].y, acc[i].y);
        acc[i].z = fmaf(p[i].z, l[2].z, acc[i].z);
        acc[i].w = fmaf(p[i].z, l[2].w, acc[i].w);
        acc[i].x = fmaf(p[i].w, l[3].x, acc[i].x);
        acc[i].y = fmaf(p[i].w, l[3].y, acc[i].y);
        acc[i].z = fmaf(p[i].w, l[3].z, acc[i].z);
        acc[i].w = fmaf(p[i].w, l[3].w, acc[i].w);
      }
    }
    __syncthreads();
  }

  // merge js partials
#pragma unroll
  for (int i = 0; i < 4; ++i)
    *(float4*)&accm[rg * 4 + i][js][dq * 4] = acc[i];
  if (dq == 0) {
#pragma unroll
    for (int i = 0; i < 4; ++i) lsb[rg * 4 + i][js] = lsum4[i];
  }
  __syncthreads();

  const int r2 = tid >> 4;       // 0..15 (row)
  const int dd = tid & 15;       // 0..15, 2 dims each
  float o0 = 0.f, o1 = 0.f, ls = 0.f;
#pragma unroll
  for (int g = 0; g < 8; ++g) {
    float2 a2 = *(const float2*)&accm[r2][g][dd * 2];
    o0 += a2.x;
    o1 += a2.y;
    ls += lsb[r2][g];
  }
  const float li = 1.0f / ls;
  o0 *= li;
  o1 *= li;
  float un2 = fmaf(o0, o0, o1 * o1);
#pragma unroll
  for (int m = 8; m >= 1; m >>= 1) un2 += __shfl_xor(un2, m, 16);
  float un = sqrtf(fmaxf(un2, 1e-15f));
  float f = tanh_fast(un) / un;        // expmap0 factor (SC = 1)
  float2 ov = make_float2(o0 * f, o1 * f);
  *(float2*)&out[(size_t)(b * Sc + sq0 + r2) * Ec + h * Dc + dd * 2] = ov;
}

// ---------------------------------------------------------------------------
// Per-row hyp_linear epilogue for the output projection (sums KSO partials)
// ---------------------------------------------------------------------------
__global__ __launch_bounds__(256) void proj_stats(
    const float* __restrict__ xin, const float* __restrict__ mx,
    const float* __restrict__ bo, float* __restrict__ out) {
  const int t = threadIdx.x;
  const int row = blockIdx.x;
  const size_t idx = (size_t)row * Ec + t;
  const float xv = xin[idx];
  float m = 0.f;
#pragma unroll
  for (int p = 0; p < KSO; ++p) m += mx[idx + (size_t)p * NEc];
  const float bb = bo[t];
  float vals[4] = {xv * xv, m * m, m * bb, bb * bb};
  __shared__ float red[4][4];
  __shared__ float fin[4];
#pragma unroll
  for (int i = 0; i < 4; ++i) {
    float v = fullWaveSum(vals[i]);
    if ((t & 63) == 0) red[i][t >> 6] = v;
  }
  __syncthreads();
  if (t < 4) fin[t] = red[t][0] + red[t][1] + red[t][2] + red[t][3];
  __syncthreads();

  float x2 = fin[0], mx2 = fin[1], mxb = fin[2], b2 = fin[3];
  float xn = sqrtf(fmaxf(x2, 1e-15f));
  float mxn = sqrtf(fmaxf(mx2, 1e-15f));
  float scl = tanh_fast((mxn / xn) * atanh_fast(fminf(xn, MAXNORM))) / mxn;
  float mvv = scl * m;
  float X2 = scl * scl * mx2;
  float XY = scl * mxb;
  float numc = 1.0f + 2.0f * XY + b2;
  float den = 1.0f + 2.0f * XY + X2 * b2 + 1e-15f;
  out[idx] = (numc * mvv + (1.0f - X2) * bb) / den;
}

extern "C" void kernel_launch(void* const* d_in, const int* in_sizes, int n_in,
                              void* d_out, int out_size, void* d_ws, size_t ws_size,
                              hipStream_t stream) {
  (void)in_sizes; (void)n_in; (void)out_size; (void)ws_size;
  const float* x  = (const float*)d_in[0];
  const float* Wq = (const float*)d_in[1];
  const float* bq = (const float*)d_in[2];
  const float* Wk = (const float*)d_in[3];
  const float* bk = (const float*)d_in[4];
  const float* Wv = (const float*)d_in[5];
  const float* bv = (const float*)d_in[6];
  const float* Wo = (const float*)d_in[7];
  const float* bo = (const float*)d_in[8];
  const float* hs = (const float*)d_in[9];

  float* ws = (float*)d_ws;
  const int NE = NEc;            // 262144
  const int NH = NROWS;          // 8192
  float* mxq = ws;               // KSQ*NE partials each
  float* mxk = mxq + KSQ * NE;
  float* mxv = mxk + KSQ * NE;
  float* mxo = mxv + KSQ * NE;   // KSO*NE partials
  float* qb  = mxo + KSO * NE;
  float* kb  = qb + NE;
  float* lvb = kb + NE;
  float* aob = lvb + NE;
  float* qnb = aob + NE;
  float* knb = qnb + NH;
  float* Pb  = knb + NH;         // 16 * 512 * 512 floats (16.8 MB)

  const int M = Bc * Sc;  // 1024 rows

  gemm_xwt<<<dim3(M / 32, 12, KSQ), 128, 0, stream>>>(x, Wq, Wk, Wv,
                                                      mxq, mxk, mxv, 2);
  qkv_stats<<<M, 256, 0, stream>>>(x, mxq, mxk, mxv, bq, bk, bv,
                                   qb, kb, lvb, qnb, knb);
  score_kernel<<<dim3(8, 8, 16), 256, 0, stream>>>(qb, kb, qnb, knb, hs, Pb);
  pv_kernel<<<dim3(32, 16), 256, 0, stream>>>(Pb, lvb, aob);
  gemm_xwt<<<dim3(M / 32, 4, KSO), 128, 0, stream>>>(aob, Wo, Wo, Wo,
                                                     mxo, mxo, mxo, 1);
  proj_stats<<<M, 256, 0, stream>>>(aob, mxo, bo, (float*)d_out);
}